// Round 1
// baseline (61913.654 us; speedup 1.0000x reference)
//
#include <hip/hip_runtime.h>
#include <stdint.h>

// RNNLayer: h_t = tanh([x_t, h_{t-1}] @ W + b), outputs all h_t [B,T,H] fp32.
// B=64, T=1024, D=1024, H=1024.  W: [D+H, H] fp32.
//
// Phase 1: XP = x @ W[:D] + b  -> written into d_out (XP overwritten by h later).
//          bf16 MFMA 16x16x32, 128x128 tiles, inline fp32->bf16 LDS staging.
// Phase 2: persistent kernel, 256 WGs = 4 row-groups(16 batch rows) x 64 col-groups(16 cols).
//          Wh[:,16] slice packed once into LDS as bf16 B-fragments.
//          Per step: read H_{t-1}[16,1024] fp32 from d_out, MFMA (K split over 4 waves),
//          reduce in LDS, += XP (in place in d_out), tanh, store, release-count.
//          Sync: per-(step,row-group) counters in d_ws, agent-scope atomics + threadfence.

#define T_LEN 1024
#define HID   1024
#define BATCH 64

typedef float  f32x4  __attribute__((ext_vector_type(4)));
typedef __bf16 bf16x8 __attribute__((ext_vector_type(8)));

// ---------------- Phase 1: x_proj GEMM ----------------
__global__ __launch_bounds__(256) void xproj_gemm(
    const float* __restrict__ x, const float* __restrict__ W,
    const float* __restrict__ bias, float* __restrict__ out)
{
    __shared__ __align__(16) __bf16 As[128][40];   // [row][k], +8 pad
    __shared__ __align__(16) __bf16 Bs[128][40];   // [col][k] (W^T slice), k XOR-swizzled

    const int bid = blockIdx.x;
    const int n0  = (bid & 7) << 7;                 // 8 col tiles
    const int64_t r0 = (int64_t)(bid >> 3) << 7;    // 512 row tiles (consecutive bids share rows -> L2)
    const int tid  = threadIdx.x;
    const int lane = tid & 63;
    const int w    = tid >> 6;
    const int hi   = lane >> 4, lo = lane & 15;
    const int wm   = (w >> 1) << 6, wn = (w & 1) << 6;  // wave's 64x64 quadrant

    f32x4 acc[4][4] = {};

    const int arow = tid >> 1, akh = (tid & 1) << 4;    // A staging: 2 thr/row, 16 fp32 each
    const int bk   = tid >> 3, bnh = (tid & 7) << 4;    // B staging: thr -> (k, 16 cols)

    for (int k0 = 0; k0 < 1024; k0 += 32) {
        {   // stage A (x rows, k-contiguous)
            const float* src = x + (r0 + arow) * 1024 + k0 + akh;
            bf16x8 t0, t1;
            #pragma unroll
            for (int i2 = 0; i2 < 8; ++i2) { t0[i2] = (__bf16)src[i2]; t1[i2] = (__bf16)src[8 + i2]; }
            *(bf16x8*)&As[arow][akh]     = t0;
            *(bf16x8*)&As[arow][akh + 8] = t1;
        }
        {   // stage B transposed into [col][k], k swizzled by col bit4-5 to break bank aliasing
            const float* src = W + (int64_t)(k0 + bk) * 1024 + n0 + bnh;
            #pragma unroll
            for (int i2 = 0; i2 < 16; ++i2) {
                int col = bnh + i2;
                Bs[col][bk ^ (((col >> 4) & 3) << 3)] = (__bf16)src[i2];
            }
        }
        __syncthreads();

        bf16x8 af[4], bfr[4];
        #pragma unroll
        for (int f = 0; f < 4; ++f)
            af[f] = *(const bf16x8*)&As[wm + f * 16 + lo][hi << 3];
        #pragma unroll
        for (int f = 0; f < 4; ++f) {
            const int cswz = (((wn >> 4) + f) & 3) << 3;
            bfr[f] = *(const bf16x8*)&Bs[wn + f * 16 + lo][(hi << 3) ^ cswz];
        }
        #pragma unroll
        for (int fm = 0; fm < 4; ++fm)
            #pragma unroll
            for (int fn = 0; fn < 4; ++fn)
                acc[fm][fn] = __builtin_amdgcn_mfma_f32_16x16x32_bf16(af[fm], bfr[fn], acc[fm][fn], 0, 0, 0);
        __syncthreads();
    }

    // epilogue: D lane mapping col=lane&15, row=(lane>>4)*4+reg  [m89-verified]
    #pragma unroll
    for (int fm = 0; fm < 4; ++fm) {
        const int64_t mrow = r0 + wm + fm * 16 + hi * 4;
        #pragma unroll
        for (int fn = 0; fn < 4; ++fn) {
            const int col = n0 + wn + fn * 16 + lo;
            const float bv = bias[col];
            #pragma unroll
            for (int r = 0; r < 4; ++r)
                out[(mrow + r) * 1024 + col] = acc[fm][fn][r] + bv;
        }
    }
}

// ---------------- Phase 2: persistent recurrent scan ----------------
__global__ __launch_bounds__(256) void rnn_scan(
    const float* __restrict__ W, float* __restrict__ out, int* __restrict__ cnt)
{
    __shared__ __align__(16) __bf16 WhS[32][64][8];  // 32 K-steps x 64 lanes x 8 bf16 = 32 KB
    __shared__ float red[4][16][16];                 // per-wave partial C tiles

    const int bid = blockIdx.x;
    const int ig  = bid >> 6;        // row group: batch rows 16*ig..+15
    const int jg  = bid & 63;        // col group: hidden cols 16*jg..+15
    const int tid = threadIdx.x;
    const int lane = tid & 63;
    const int w   = tid >> 6;        // wave -> K quarter
    const int hi  = lane >> 4, lo = lane & 15;

    // Pack Wh[:, 16*jg..] as B-fragments: WhS[kb][lane][ii] = Wh[kb*32+hi*8+ii][16*jg+lo]
    for (int kb = w * 8; kb < w * 8 + 8; ++kb) {
        const float* src = W + (int64_t)(1024 + kb * 32 + hi * 8) * 1024 + jg * 16 + lo;
        bf16x8 t;
        #pragma unroll
        for (int ii = 0; ii < 8; ++ii) t[ii] = (__bf16)src[(int64_t)ii * 1024];
        *(bf16x8*)&WhS[kb][lane][0] = t;
    }
    __syncthreads();

    const int64_t rstride = (int64_t)T_LEN * HID;
    const float* habase = out + (int64_t)(ig * 16 + lo) * rstride;  // A-frag row = lane&15
    const int m = tid >> 4, n = tid & 15;
    float* pobase = out + (int64_t)(ig * 16 + m) * rstride + jg * 16 + n;

    for (int t = 0; t < T_LEN; ++t) {
        f32x4 acc = {0.f, 0.f, 0.f, 0.f};
        if (t > 0) {
            // wait for all 64 producers of row group ig at step t-1
            const int* c = cnt + (t - 1) * 4 + ig;
            while (__hip_atomic_load(c, __ATOMIC_RELAXED, __HIP_MEMORY_SCOPE_AGENT) < 64)
                __builtin_amdgcn_s_sleep(1);
            __threadfence();  // acquire: invalidate stale L1/L2 before reading peers' h

            const float* hb = habase + (int64_t)(t - 1) * HID + hi * 8;
            #pragma unroll
            for (int kb2 = 0; kb2 < 8; ++kb2) {
                const int kb = w * 8 + kb2;
                f32x4 v0 = *(const f32x4*)(hb + kb * 32);
                f32x4 v1 = *(const f32x4*)(hb + kb * 32 + 4);
                bf16x8 a;
                a[0] = (__bf16)v0.x; a[1] = (__bf16)v0.y; a[2] = (__bf16)v0.z; a[3] = (__bf16)v0.w;
                a[4] = (__bf16)v1.x; a[5] = (__bf16)v1.y; a[6] = (__bf16)v1.z; a[7] = (__bf16)v1.w;
                acc = __builtin_amdgcn_mfma_f32_16x16x32_bf16(
                          a, *(const bf16x8*)&WhS[kb][lane][0], acc, 0, 0, 0);
            }
        }
        // K-split reduction across the 4 waves
        red[w][hi * 4 + 0][lo] = acc[0];
        red[w][hi * 4 + 1][lo] = acc[1];
        red[w][hi * 4 + 2][lo] = acc[2];
        red[w][hi * 4 + 3][lo] = acc[3];
        __syncthreads();

        float s = red[0][m][n] + red[1][m][n] + red[2][m][n] + red[3][m][n];
        float* po = pobase + (int64_t)t * HID;   // XP tile, overwritten in place with h
        float h = tanhf(*po + s);
        *po = h;

        __threadfence();   // release: drain this thread's h stores to coherent point
        __syncthreads();   // all threads' fences done, red[] safe to reuse
        if (tid == 0)
            __hip_atomic_fetch_add(&cnt[t * 4 + ig], 1, __ATOMIC_RELEASE, __HIP_MEMORY_SCOPE_AGENT);
    }
}

extern "C" void kernel_launch(void* const* d_in, const int* in_sizes, int n_in,
                              void* d_out, int out_size, void* d_ws, size_t ws_size,
                              hipStream_t stream)
{
    const float* x    = (const float*)d_in[0];   // [64,1024,1024]
    const float* W    = (const float*)d_in[1];   // [2048,1024]
    const float* bias = (const float*)d_in[2];   // [1024]
    float* out = (float*)d_out;                  // [64,1024,1024]
    int*   cnt = (int*)d_ws;                     // 1024 steps x 4 row-groups

    hipMemsetAsync(cnt, 0, T_LEN * 4 * sizeof(int), stream);
    xproj_gemm<<<dim3(4096), dim3(256), 0, stream>>>(x, W, bias, out);
    rnn_scan<<<dim3(256), dim3(256), 0, stream>>>(W, out, cnt);
}

// Round 3
// 12929.225 us; speedup vs baseline: 4.7887x; 4.7887x over previous
//
#include <hip/hip_runtime.h>
#include <stdint.h>

// RNNLayer: h_t = tanh([x_t, h_{t-1}] @ W + b), outputs all h_t [B,T,H] fp32.
// B=64, T=1024, D=1024, H=1024.  W: [D+H, H] fp32.
//
// Phase 1: XP = x @ W[:D] + b -> d_out (bf16 MFMA, 128x128 tiles).
// Phase 2: persistent scan, 256 WGs = 4 row-rings x 64 col-groups.
//   Round-3 change: self-validating exchange words. h is exchanged as
//   u32 = {step_tag:16 | bf16(h):16} stored/loaded with relaxed AGENT-scope
//   atomics (sc1 path, L2-bypass to IF). Tag travels IN the same atomic word
//   as the data -> no cross-address release/acquire ordering needed at all
//   (round 2 raced: flag fetch_add could reach IF before sc1 data stores).
//   Consumers spin until all words of their slab carry tag==t.
//   rd[] counter remains only as a WAR throttle on slot reuse (monotone,
//   relaxed-read-safe in that role). 2 slots x 64x1024 u32, zeroed each launch.

#define T_LEN 1024
#define HID   1024

typedef float  f32x4  __attribute__((ext_vector_type(4)));
typedef __bf16 bf16x8 __attribute__((ext_vector_type(8)));
typedef unsigned long long u64;

// ---------------- Phase 1: x_proj GEMM ----------------
__global__ __launch_bounds__(256) void xproj_gemm(
    const float* __restrict__ x, const float* __restrict__ W,
    const float* __restrict__ bias, float* __restrict__ out)
{
    __shared__ __align__(16) __bf16 As[128][40];
    __shared__ __align__(16) __bf16 Bs[128][40];

    const int bid = blockIdx.x;
    const int n0  = (bid & 7) << 7;
    const int64_t r0 = (int64_t)(bid >> 3) << 7;
    const int tid  = threadIdx.x;
    const int lane = tid & 63;
    const int w    = tid >> 6;
    const int hi   = lane >> 4, lo = lane & 15;
    const int wm   = (w >> 1) << 6, wn = (w & 1) << 6;

    f32x4 acc[4][4] = {};

    const int arow = tid >> 1, akh = (tid & 1) << 4;
    const int bk   = tid >> 3, bnh = (tid & 7) << 4;

    for (int k0 = 0; k0 < 1024; k0 += 32) {
        {
            const float* src = x + (r0 + arow) * 1024 + k0 + akh;
            bf16x8 t0, t1;
            #pragma unroll
            for (int i2 = 0; i2 < 8; ++i2) { t0[i2] = (__bf16)src[i2]; t1[i2] = (__bf16)src[8 + i2]; }
            *(bf16x8*)&As[arow][akh]     = t0;
            *(bf16x8*)&As[arow][akh + 8] = t1;
        }
        {
            const float* src = W + (int64_t)(k0 + bk) * 1024 + n0 + bnh;
            #pragma unroll
            for (int i2 = 0; i2 < 16; ++i2) {
                int col = bnh + i2;
                Bs[col][bk ^ (((col >> 4) & 3) << 3)] = (__bf16)src[i2];
            }
        }
        __syncthreads();

        bf16x8 af[4], bfr[4];
        #pragma unroll
        for (int f = 0; f < 4; ++f)
            af[f] = *(const bf16x8*)&As[wm + f * 16 + lo][hi << 3];
        #pragma unroll
        for (int f = 0; f < 4; ++f) {
            const int cswz = (((wn >> 4) + f) & 3) << 3;
            bfr[f] = *(const bf16x8*)&Bs[wn + f * 16 + lo][(hi << 3) ^ cswz];
        }
        #pragma unroll
        for (int fm = 0; fm < 4; ++fm)
            #pragma unroll
            for (int fn = 0; fn < 4; ++fn)
                acc[fm][fn] = __builtin_amdgcn_mfma_f32_16x16x32_bf16(af[fm], bfr[fn], acc[fm][fn], 0, 0, 0);
        __syncthreads();
    }

    #pragma unroll
    for (int fm = 0; fm < 4; ++fm) {
        const int64_t mrow = r0 + wm + fm * 16 + hi * 4;
        #pragma unroll
        for (int fn = 0; fn < 4; ++fn) {
            const int col = n0 + wn + fn * 16 + lo;
            const float bv = bias[col];
            #pragma unroll
            for (int r = 0; r < 4; ++r)
                out[(mrow + r) * 1024 + col] = acc[fm][fn][r] + bv;
        }
    }
}

// ---------------- Phase 2: persistent recurrent scan ----------------
__global__ __launch_bounds__(256) void rnn_scan(
    const float* __restrict__ W, float* __restrict__ out,
    int* __restrict__ rd, unsigned int* __restrict__ hx)
{
    __shared__ __align__(16) __bf16 WhS[32][64][8];  // 32 KB: Wh[:,16-col slice] B-frags
    __shared__ float red[4][16][16];                 // K-split partial C tiles

    const int bid = blockIdx.x;
    const int ig  = bid >> 6;        // row ring: batch rows 16*ig..+15
    const int jg  = bid & 63;        // col group: hidden cols 16*jg..+15
    const int tid = threadIdx.x;
    const int lane = tid & 63;
    const int w   = tid >> 6;        // wave -> K quarter
    const int hi  = lane >> 4, lo = lane & 15;

    // Pack Wh[:, 16*jg..] as B-fragments: WhS[kb][lane][ii] = Wh[kb*32+hi*8+ii][16*jg+lo]
    for (int kb = w * 8; kb < w * 8 + 8; ++kb) {
        const float* src = W + (int64_t)(1024 + kb * 32 + hi * 8) * 1024 + jg * 16 + lo;
        bf16x8 t;
        #pragma unroll
        for (int ii = 0; ii < 8; ++ii) t[ii] = (__bf16)src[(int64_t)ii * 1024];
        *(bf16x8*)&WhS[kb][lane][0] = t;
    }
    __syncthreads();

    const int64_t rstride = (int64_t)T_LEN * HID;
    const int m = tid >> 4, n = tid & 15;
    float* pobase = out + (int64_t)(ig * 16 + m) * rstride + jg * 16 + n;

    const int rd_row  = ig * 16 + lo;                 // A-frag row (lane&15)
    const int wr_idx  = (ig * 16 + m) * 1024 + jg * 16 + n;  // producer word index

    for (int t = 0; t < T_LEN; ++t) {
        float* po = pobase + (int64_t)t * HID;
        float xpv = *po;                      // XP prefetch (overlaps the tag spin)

        f32x4 acc = {0.f, 0.f, 0.f, 0.f};
        if (t > 0) {
            const unsigned int exptag = (unsigned int)t;   // h_{t-1} carries tag t
            const u64* bp = (const u64*)(hx + ((t - 1) & 1) * 65536
                                            + rd_row * 1024 + w * 256 + hi * 8);
            u64 q[32];
            bool bad;
            do {
                #pragma unroll
                for (int j = 0; j < 32; ++j)   // kb2=(j>>2): 16 u64/kb2-block, (j&3) within
                    q[j] = __hip_atomic_load(bp + (j >> 2) * 16 + (j & 3),
                                             __ATOMIC_RELAXED, __HIP_MEMORY_SCOPE_AGENT);
                unsigned int badm = 0;
                #pragma unroll
                for (int j = 0; j < 32; ++j) {
                    badm |= ((unsigned int)(q[j] >> 16) & 0xffffu) ^ exptag;
                    badm |= ((unsigned int)(q[j] >> 48)) ^ exptag;
                }
                bad = (badm != 0);
                if (bad) __builtin_amdgcn_s_sleep(2);
            } while (bad);

            #pragma unroll
            for (int kb2 = 0; kb2 < 8; ++kb2) {
                bf16x8 a;
                #pragma unroll
                for (int p = 0; p < 4; ++p) {
                    u64 v = q[kb2 * 4 + p];
                    a[p * 2]     = __builtin_bit_cast(__bf16, (unsigned short)(v & 0xffffu));
                    a[p * 2 + 1] = __builtin_bit_cast(__bf16, (unsigned short)((v >> 32) & 0xffffu));
                }
                acc = __builtin_amdgcn_mfma_f32_16x16x32_bf16(
                          a, *(const bf16x8*)&WhS[w * 8 + kb2][lane][0], acc, 0, 0, 0);
            }
        }

        // K-split reduction across the 4 waves
        red[w][hi * 4 + 0][lo] = acc[0];
        red[w][hi * 4 + 1][lo] = acc[1];
        red[w][hi * 4 + 2][lo] = acc[2];
        red[w][hi * 4 + 3][lo] = acc[3];
        __syncthreads();
        // all waves' h_{t-1} loads have retired (consumed by MFMA before barrier):
        // signal "this WG finished reading slot (t-1)&1"
        if (t > 0 && tid == 0)
            __hip_atomic_fetch_add(&rd[t * 4 + ig], 1,
                                   __ATOMIC_RELAXED, __HIP_MEMORY_SCOPE_AGENT);

        float s = red[0][m][n] + red[1][m][n] + red[2][m][n] + red[3][m][n];
        float h = tanhf(xpv + s);
        *po = h;                               // fp32 output, normal cached store (private)

        // WAR throttle: before overwriting slot t&1 (holds h_{t-2}), wait until
        // all 64 ring members finished reading it (their step t-1 reads).
        if (t >= 2 && tid == 0) {
            const int* c = rd + (t - 1) * 4 + ig;
            while (__hip_atomic_load(c, __ATOMIC_RELAXED, __HIP_MEMORY_SCOPE_AGENT) < 64)
                __builtin_amdgcn_s_sleep(2);
        }
        __syncthreads();                       // gate all threads on tid0's throttle

        // self-validating store: {tag=t+1 | bf16(h)} in ONE atomic word
        unsigned short hb = __builtin_bit_cast(unsigned short, (__bf16)h);
        __hip_atomic_store(hx + (t & 1) * 65536 + wr_idx,
                           ((unsigned int)(t + 1) << 16) | (unsigned int)hb,
                           __ATOMIC_RELAXED, __HIP_MEMORY_SCOPE_AGENT);
    }
}

extern "C" void kernel_launch(void* const* d_in, const int* in_sizes, int n_in,
                              void* d_out, int out_size, void* d_ws, size_t ws_size,
                              hipStream_t stream)
{
    const float* x    = (const float*)d_in[0];   // [64,1024,1024]
    const float* W    = (const float*)d_in[1];   // [2048,1024]
    const float* bias = (const float*)d_in[2];   // [1024]
    float* out = (float*)d_out;                  // [64,1024,1024]

    int*          rd = (int*)d_ws;                              // 1024*4 ints = 16 KB
    unsigned int* hx = (unsigned int*)((char*)d_ws + 16384);    // 2 x 64x1024 u32 = 512 KB

    hipMemsetAsync(d_ws, 0, 16384 + 524288, stream);            // rd=0, tags=0 (never expected)
    xproj_gemm<<<dim3(4096), dim3(256), 0, stream>>>(x, W, bias, out);
    rnn_scan<<<dim3(256), dim3(256), 0, stream>>>(W, out, rd, hx);
}

// Round 4
// 8173.299 us; speedup vs baseline: 7.5751x; 1.5819x over previous
//
#include <hip/hip_runtime.h>
#include <stdint.h>

// RNNLayer: h_t = tanh([x_t, h_{t-1}] @ W + b), outputs all h_t [B,T,H] fp32.
// B=64, T=1024, D=1024, H=1024.  W: [D+H, H] fp32.
//
// Phase 1: XP = x @ W[:D] + b -> d_out (bf16 MFMA, 128x128 tiles).
// Phase 2: persistent scan, 256 WGs = 4 row-rings x 64 col-groups.
//   h exchanged as u32 = {step_tag:16 | bf16(h):16} via relaxed AGENT atomics
//   (self-validating word: no cross-address ordering needed).
//   Round-4 change: rd[] counter REMOVED. The tag spin itself proves WAR
//   safety with 2 slots: observing tag t from writer M implies M finished
//   step t-1, which (data dependency) implies M's reads of slot t&1's old
//   content (h_{t-2}) retired. Round 3 paid a serialized 64-way fetch_add
//   fan-in + a second cross-device throttle wait per step for nothing.
//   Also: exchange store issued before the fp32 out store; fast exp2-based
//   tanh; padded reduce tile (LDS conflict-free).

#define T_LEN 1024
#define HID   1024

typedef float  f32x4  __attribute__((ext_vector_type(4)));
typedef __bf16 bf16x8 __attribute__((ext_vector_type(8)));
typedef unsigned long long u64;

// ---------------- Phase 1: x_proj GEMM ----------------
__global__ __launch_bounds__(256) void xproj_gemm(
    const float* __restrict__ x, const float* __restrict__ W,
    const float* __restrict__ bias, float* __restrict__ out)
{
    __shared__ __align__(16) __bf16 As[128][40];
    __shared__ __align__(16) __bf16 Bs[128][40];

    const int bid = blockIdx.x;
    const int n0  = (bid & 7) << 7;
    const int64_t r0 = (int64_t)(bid >> 3) << 7;
    const int tid  = threadIdx.x;
    const int lane = tid & 63;
    const int w    = tid >> 6;
    const int hi   = lane >> 4, lo = lane & 15;
    const int wm   = (w >> 1) << 6, wn = (w & 1) << 6;

    f32x4 acc[4][4] = {};

    const int arow = tid >> 1, akh = (tid & 1) << 4;
    const int bk   = tid >> 3, bnh = (tid & 7) << 4;

    for (int k0 = 0; k0 < 1024; k0 += 32) {
        {
            const float* src = x + (r0 + arow) * 1024 + k0 + akh;
            bf16x8 t0, t1;
            #pragma unroll
            for (int i2 = 0; i2 < 8; ++i2) { t0[i2] = (__bf16)src[i2]; t1[i2] = (__bf16)src[8 + i2]; }
            *(bf16x8*)&As[arow][akh]     = t0;
            *(bf16x8*)&As[arow][akh + 8] = t1;
        }
        {
            const float* src = W + (int64_t)(k0 + bk) * 1024 + n0 + bnh;
            #pragma unroll
            for (int i2 = 0; i2 < 16; ++i2) {
                int col = bnh + i2;
                Bs[col][bk ^ (((col >> 4) & 3) << 3)] = (__bf16)src[i2];
            }
        }
        __syncthreads();

        bf16x8 af[4], bfr[4];
        #pragma unroll
        for (int f = 0; f < 4; ++f)
            af[f] = *(const bf16x8*)&As[wm + f * 16 + lo][hi << 3];
        #pragma unroll
        for (int f = 0; f < 4; ++f) {
            const int cswz = (((wn >> 4) + f) & 3) << 3;
            bfr[f] = *(const bf16x8*)&Bs[wn + f * 16 + lo][(hi << 3) ^ cswz];
        }
        #pragma unroll
        for (int fm = 0; fm < 4; ++fm)
            #pragma unroll
            for (int fn = 0; fn < 4; ++fn)
                acc[fm][fn] = __builtin_amdgcn_mfma_f32_16x16x32_bf16(af[fm], bfr[fn], acc[fm][fn], 0, 0, 0);
        __syncthreads();
    }

    #pragma unroll
    for (int fm = 0; fm < 4; ++fm) {
        const int64_t mrow = r0 + wm + fm * 16 + hi * 4;
        #pragma unroll
        for (int fn = 0; fn < 4; ++fn) {
            const int col = n0 + wn + fn * 16 + lo;
            const float bv = bias[col];
            #pragma unroll
            for (int r = 0; r < 4; ++r)
                out[(mrow + r) * 1024 + col] = acc[fm][fn][r] + bv;
        }
    }
}

// fast tanh: 1 - 2/(exp(2x)+1); saturates correctly for |x| large.
__device__ __forceinline__ float tanh_fast(float x) {
    float e = __builtin_amdgcn_exp2f(x * 2.885390082f);   // e^(2x) = 2^(2x*log2 e)
    return 1.0f - 2.0f * __builtin_amdgcn_rcpf(e + 1.0f);
}

// ---------------- Phase 2: persistent recurrent scan ----------------
__global__ __launch_bounds__(256) void rnn_scan(
    const float* __restrict__ W, float* __restrict__ out,
    unsigned int* __restrict__ hx)
{
    __shared__ __align__(16) __bf16 WhS[32][64][8];  // 32 KB: Wh[:,16-col slice] B-frags
    __shared__ float red[4][16][17];                 // K-split partials, padded (bank-safe)

    const int bid = blockIdx.x;
    const int ig  = bid >> 6;        // row ring: batch rows 16*ig..+15
    const int jg  = bid & 63;        // col group: hidden cols 16*jg..+15
    const int tid = threadIdx.x;
    const int lane = tid & 63;
    const int w   = tid >> 6;        // wave -> K quarter
    const int hi  = lane >> 4, lo = lane & 15;

    // Pack Wh[:, 16*jg..] as B-fragments: WhS[kb][lane][ii] = Wh[kb*32+hi*8+ii][16*jg+lo]
    for (int kb = w * 8; kb < w * 8 + 8; ++kb) {
        const float* src = W + (int64_t)(1024 + kb * 32 + hi * 8) * 1024 + jg * 16 + lo;
        bf16x8 t;
        #pragma unroll
        for (int ii = 0; ii < 8; ++ii) t[ii] = (__bf16)src[(int64_t)ii * 1024];
        *(bf16x8*)&WhS[kb][lane][0] = t;
    }
    __syncthreads();

    const int64_t rstride = (int64_t)T_LEN * HID;
    const int m = tid >> 4, n = tid & 15;
    float* pobase = out + (int64_t)(ig * 16 + m) * rstride + jg * 16 + n;

    const int rd_row = ig * 16 + lo;                          // A-frag row (lane&15)
    const int wr_idx = (ig * 16 + m) * 1024 + jg * 16 + n;    // producer word index

    for (int t = 0; t < T_LEN; ++t) {
        float* po = pobase + (int64_t)t * HID;
        float xpv = *po;                      // XP prefetch (overlaps the tag spin)

        f32x4 acc = {0.f, 0.f, 0.f, 0.f};
        if (t > 0) {
            const unsigned int exptag = (unsigned int)t;   // h_{t-1} carries tag t
            const u64* bp = (const u64*)(hx + ((t - 1) & 1) * 65536
                                            + rd_row * 1024 + w * 256 + hi * 8);
            u64 q[32];
            bool bad;
            do {
                #pragma unroll
                for (int j = 0; j < 32; ++j)   // kb2=(j>>2), (j&3) within kb2-block
                    q[j] = __hip_atomic_load(bp + (j >> 2) * 16 + (j & 3),
                                             __ATOMIC_RELAXED, __HIP_MEMORY_SCOPE_AGENT);
                unsigned int badm = 0;
                #pragma unroll
                for (int j = 0; j < 32; ++j) {
                    badm |= ((unsigned int)(q[j] >> 16) & 0xffffu) ^ exptag;
                    badm |= ((unsigned int)(q[j] >> 48)) ^ exptag;
                }
                bad = (badm != 0);
                if (bad) __builtin_amdgcn_s_sleep(1);
            } while (bad);

            #pragma unroll
            for (int kb2 = 0; kb2 < 8; ++kb2) {
                bf16x8 a;
                #pragma unroll
                for (int p = 0; p < 4; ++p) {
                    u64 v = q[kb2 * 4 + p];
                    a[p * 2]     = __builtin_bit_cast(__bf16, (unsigned short)(v & 0xffffu));
                    a[p * 2 + 1] = __builtin_bit_cast(__bf16, (unsigned short)((v >> 32) & 0xffffu));
                }
                acc = __builtin_amdgcn_mfma_f32_16x16x32_bf16(
                          a, *(const bf16x8*)&WhS[w * 8 + kb2][lane][0], acc, 0, 0, 0);
            }
        }

        // K-split reduction across the 4 waves
        red[w][hi * 4 + 0][lo] = acc[0];
        red[w][hi * 4 + 1][lo] = acc[1];
        red[w][hi * 4 + 2][lo] = acc[2];
        red[w][hi * 4 + 3][lo] = acc[3];
        __syncthreads();

        float s = red[0][m][n] + red[1][m][n] + red[2][m][n] + red[3][m][n];
        float h = tanh_fast(xpv + s);

        // cross-WG-visible store FIRST: {tag=t+1 | bf16(h)} in one atomic word.
        // WAR-safe without any counter: our spin this step observed tag t from
        // every ring WG => they all finished step t-1 => their reads of this
        // slot's old content (h_{t-2}) have retired.
        unsigned short hb = __builtin_bit_cast(unsigned short, (__bf16)h);
        __hip_atomic_store(hx + (t & 1) * 65536 + wr_idx,
                           ((unsigned int)(t + 1) << 16) | (unsigned int)hb,
                           __ATOMIC_RELAXED, __HIP_MEMORY_SCOPE_AGENT);

        *po = h;                               // fp32 output, normal cached store

        __syncthreads();                       // protect red[] for next iteration
    }
}

extern "C" void kernel_launch(void* const* d_in, const int* in_sizes, int n_in,
                              void* d_out, int out_size, void* d_ws, size_t ws_size,
                              hipStream_t stream)
{
    const float* x    = (const float*)d_in[0];   // [64,1024,1024]
    const float* W    = (const float*)d_in[1];   // [2048,1024]
    const float* bias = (const float*)d_in[2];   // [1024]
    float* out = (float*)d_out;                  // [64,1024,1024]

    unsigned int* hx = (unsigned int*)d_ws;      // 2 slots x 64x1024 u32 = 512 KB

    hipMemsetAsync(hx, 0, 524288, stream);       // zero tags (expected tags are >= 1)
    xproj_gemm<<<dim3(4096), dim3(256), 0, stream>>>(x, W, bias, out);
    rnn_scan<<<dim3(256), dim3(256), 0, stream>>>(W, out, hx);
}

// Round 5
// 8001.630 us; speedup vs baseline: 7.7376x; 1.0215x over previous
//
#include <hip/hip_runtime.h>
#include <stdint.h>

// RNNLayer: h_t = tanh([x_t, h_{t-1}] @ W + b), outputs all h_t [B,T,H] fp32.
// B=64, T=1024, D=1024, H=1024.  W: [D+H, H] fp32.
//
// Phase 1: XP = x @ W[:D] + b -> d_out (bf16 MFMA, 128x128 tiles).
// Phase 2: persistent scan. Round-5 change: 32 fat WGs (4 rings x 8 col-groups,
//   512 thr, 128 cols/WG) instead of 256 thin ones. Round 4 was bound by
//   DUPLICATED slab reads: 256 WGs x 64KB sc1 reads = 16 MB/step through the
//   IF coherent point (~2.1 TB/s observed). Now each WG reads its ring slab
//   ONCE (distributed over 512 threads), validates tags, stages bf16 A-frags
//   into XOR-swizzled LDS; each wave holds its 16-col Wh slice in 128 VGPRs
//   (B-frags, full K) -> no cross-wave reduction, 2 MB/step exchange traffic.
//   Retries re-read only failed words. h exchanged as u32={tag:16|bf16:16}
//   relaxed AGENT atomics (self-validating; WAR-safe with 2 slots by the
//   tag-implies-prior-reads-retired argument, via the WG-internal barrier).

#define T_LEN 1024
#define HID   1024

typedef float  f32x4  __attribute__((ext_vector_type(4)));
typedef __bf16 bf16x8 __attribute__((ext_vector_type(8)));
typedef unsigned long long u64;

// ---------------- Phase 1: x_proj GEMM ----------------
__global__ __launch_bounds__(256) void xproj_gemm(
    const float* __restrict__ x, const float* __restrict__ W,
    const float* __restrict__ bias, float* __restrict__ out)
{
    __shared__ __align__(16) __bf16 As[128][40];
    __shared__ __align__(16) __bf16 Bs[128][40];

    const int bid = blockIdx.x;
    const int n0  = (bid & 7) << 7;
    const int64_t r0 = (int64_t)(bid >> 3) << 7;
    const int tid  = threadIdx.x;
    const int lane = tid & 63;
    const int w    = tid >> 6;
    const int hi   = lane >> 4, lo = lane & 15;
    const int wm   = (w >> 1) << 6, wn = (w & 1) << 6;

    f32x4 acc[4][4] = {};

    const int arow = tid >> 1, akh = (tid & 1) << 4;
    const int bk   = tid >> 3, bnh = (tid & 7) << 4;

    for (int k0 = 0; k0 < 1024; k0 += 32) {
        {
            const float* src = x + (r0 + arow) * 1024 + k0 + akh;
            bf16x8 t0, t1;
            #pragma unroll
            for (int i2 = 0; i2 < 8; ++i2) { t0[i2] = (__bf16)src[i2]; t1[i2] = (__bf16)src[8 + i2]; }
            *(bf16x8*)&As[arow][akh]     = t0;
            *(bf16x8*)&As[arow][akh + 8] = t1;
        }
        {
            const float* src = W + (int64_t)(k0 + bk) * 1024 + n0 + bnh;
            #pragma unroll
            for (int i2 = 0; i2 < 16; ++i2) {
                int col = bnh + i2;
                Bs[col][bk ^ (((col >> 4) & 3) << 3)] = (__bf16)src[i2];
            }
        }
        __syncthreads();

        bf16x8 af[4], bfr[4];
        #pragma unroll
        for (int f = 0; f < 4; ++f)
            af[f] = *(const bf16x8*)&As[wm + f * 16 + lo][hi << 3];
        #pragma unroll
        for (int f = 0; f < 4; ++f) {
            const int cswz = (((wn >> 4) + f) & 3) << 3;
            bfr[f] = *(const bf16x8*)&Bs[wn + f * 16 + lo][(hi << 3) ^ cswz];
        }
        #pragma unroll
        for (int fm = 0; fm < 4; ++fm)
            #pragma unroll
            for (int fn = 0; fn < 4; ++fn)
                acc[fm][fn] = __builtin_amdgcn_mfma_f32_16x16x32_bf16(af[fm], bfr[fn], acc[fm][fn], 0, 0, 0);
        __syncthreads();
    }

    #pragma unroll
    for (int fm = 0; fm < 4; ++fm) {
        const int64_t mrow = r0 + wm + fm * 16 + hi * 4;
        #pragma unroll
        for (int fn = 0; fn < 4; ++fn) {
            const int col = n0 + wn + fn * 16 + lo;
            const float bv = bias[col];
            #pragma unroll
            for (int r = 0; r < 4; ++r)
                out[(mrow + r) * 1024 + col] = acc[fm][fn][r] + bv;
        }
    }
}

// fast tanh: 1 - 2/(exp(2x)+1); saturates correctly for |x| large.
__device__ __forceinline__ float tanh_fast(float x) {
    float e = __builtin_amdgcn_exp2f(x * 2.885390082f);
    return 1.0f - 2.0f * __builtin_amdgcn_rcpf(e + 1.0f);
}

// ---------------- Phase 2: persistent recurrent scan ----------------
// 32 WGs = 4 rings (16 batch rows) x 8 col-groups (128 cols). 512 threads.
__global__ __launch_bounds__(512, 2) void rnn_scan(
    const float* __restrict__ W, float* __restrict__ out,
    unsigned int* __restrict__ hx)
{
    // staged h_{t-1} slab as bf16 A-frags, XOR-swizzled (16B units): 32 KB
    __shared__ __align__(16) unsigned char A_lds[16 * 2048];

    const int bid = blockIdx.x;
    const int ig  = bid >> 3;        // ring: batch rows 16*ig..+15
    const int jg  = bid & 7;         // col group: hidden cols 128*jg..+127
    const int tid = threadIdx.x;
    const int lane = tid & 63;
    const int wv  = tid >> 6;        // wave -> 16-col tile
    const int hi  = lane >> 4, lo = lane & 15;

    // ---- one-time: Wh B-frags for this wave's 16 cols, ALL K, in registers ----
    // breg[kb][j] = Wh[kb*32 + hi*8 + j][jg*128 + wv*16 + lo]
    const int col = jg * 128 + wv * 16 + lo;
    bf16x8 breg[32];
    {
        const float* wb = W + (int64_t)1024 * 1024 + col;   // Wh starts at row 1024
        #pragma unroll
        for (int kb = 0; kb < 32; ++kb) {
            const float* src = wb + (int64_t)(kb * 32 + hi * 8) * 1024;
            bf16x8 tf;
            #pragma unroll
            for (int j = 0; j < 8; ++j) tf[j] = (__bf16)src[(int64_t)j * 1024];
            breg[kb] = tf;
        }
    }

    // staging role: row = tid>>5 (16 rows), 32 threads/row, 16 u64 each (k-span 32)
    const int srow = tid >> 5;
    const int c32  = tid & 31;
    const int slab_u64 = (ig * 16 + srow) * 512 + c32 * 16;   // into 64x512 u64 slot
    const unsigned swz_w = (unsigned)((srow & 7) << 4);       // stage-write XOR
    const unsigned kbyte0 = (unsigned)(c32 * 64);

    // compute role: A-frag read base for this lane
    const unsigned abase = (unsigned)(lo * 2048);
    const unsigned axor  = (unsigned)((lo & 7) << 4);

    const int64_t rstride = (int64_t)T_LEN * HID;
    float* pr0 = out + (int64_t)(ig * 16 + hi * 4) * rstride + col;  // + r*rstride + t*HID
    const int wr0 = (ig * 16 + hi * 4) * 1024 + col;                 // exchange word idx, + r*1024

    for (int t = 0; t < T_LEN; ++t) {
        // XP prefetch (normal cached loads) — overlaps the tag spin
        float xpv0 = pr0[(int64_t)t * HID];
        float xpv1 = pr0[(int64_t)t * HID + rstride];
        float xpv2 = pr0[(int64_t)t * HID + 2 * rstride];
        float xpv3 = pr0[(int64_t)t * HID + 3 * rstride];

        f32x4 accs = {0.f, 0.f, 0.f, 0.f};
        if (t > 0) {
            // ---- distributed stage+validate: each thread 16 u64 (k-span 32) ----
            const unsigned int exptag = (unsigned int)t;
            const u64* bp = (const u64*)(hx + ((t - 1) & 1) * 65536) + slab_u64;
            u64 q[16];
            #pragma unroll
            for (int j = 0; j < 16; ++j)
                q[j] = __hip_atomic_load(bp + j, __ATOMIC_RELAXED, __HIP_MEMORY_SCOPE_AGENT);
            unsigned bad = 0;
            #pragma unroll
            for (int j = 0; j < 16; ++j) {
                unsigned b = (((unsigned)(q[j] >> 16) & 0xffffu) ^ exptag)
                           | (((unsigned)(q[j] >> 48)) ^ exptag);
                bad |= (b ? 1u : 0u) << j;
            }
            while (bad) {                 // selective retry: only failed words
                __builtin_amdgcn_s_sleep(1);
                #pragma unroll
                for (int j = 0; j < 16; ++j)
                    if (bad & (1u << j)) {
                        q[j] = __hip_atomic_load(bp + j, __ATOMIC_RELAXED, __HIP_MEMORY_SCOPE_AGENT);
                        if ((((unsigned)(q[j] >> 16) & 0xffffu) == exptag) &&
                            ((unsigned)(q[j] >> 48) == exptag))
                            bad &= ~(1u << j);
                    }
            }
            // unpack {tag|bf16}x2 -> packed bf16x2 dwords via v_perm, write swizzled LDS
            unsigned dw[16];
            #pragma unroll
            for (int j = 0; j < 16; ++j)
                dw[j] = __builtin_amdgcn_perm((unsigned)(q[j] >> 32), (unsigned)q[j], 0x05040100u);
            #pragma unroll
            for (int i = 0; i < 4; ++i) {
                f32x4 v = { __builtin_bit_cast(float, dw[4 * i]),
                            __builtin_bit_cast(float, dw[4 * i + 1]),
                            __builtin_bit_cast(float, dw[4 * i + 2]),
                            __builtin_bit_cast(float, dw[4 * i + 3]) };
                *(f32x4*)(A_lds + srow * 2048 + ((kbyte0 + 16 * i) ^ swz_w)) = v;
            }
            __syncthreads();   // A slab ready

            // ---- full-K MFMA against register-resident Wh (dual accumulators) ----
            f32x4 acc0 = {0.f, 0.f, 0.f, 0.f}, acc1 = {0.f, 0.f, 0.f, 0.f};
            #pragma unroll
            for (int kb = 0; kb < 32; kb += 2) {
                bf16x8 a0 = *(const bf16x8*)(A_lds + abase + (((unsigned)(kb * 64) + hi * 16) ^ axor));
                bf16x8 a1 = *(const bf16x8*)(A_lds + abase + (((unsigned)((kb + 1) * 64) + hi * 16) ^ axor));
                acc0 = __builtin_amdgcn_mfma_f32_16x16x32_bf16(a0, breg[kb],     acc0, 0, 0, 0);
                acc1 = __builtin_amdgcn_mfma_f32_16x16x32_bf16(a1, breg[kb + 1], acc1, 0, 0, 0);
            }
            accs = acc0 + acc1;
        }

        // ---- epilogue: 4 outputs/thread (rows hi*4..+3, col) ----
        float h0 = tanh_fast(xpv0 + accs[0]);
        float h1 = tanh_fast(xpv1 + accs[1]);
        float h2 = tanh_fast(xpv2 + accs[2]);
        float h3 = tanh_fast(xpv3 + accs[3]);

        unsigned int* hxs = hx + (t & 1) * 65536 + wr0;
        const unsigned int tagw = (unsigned int)(t + 1) << 16;
        __hip_atomic_store(hxs,        tagw | __builtin_bit_cast(unsigned short, (__bf16)h0),
                           __ATOMIC_RELAXED, __HIP_MEMORY_SCOPE_AGENT);
        __hip_atomic_store(hxs + 1024, tagw | __builtin_bit_cast(unsigned short, (__bf16)h1),
                           __ATOMIC_RELAXED, __HIP_MEMORY_SCOPE_AGENT);
        __hip_atomic_store(hxs + 2048, tagw | __builtin_bit_cast(unsigned short, (__bf16)h2),
                           __ATOMIC_RELAXED, __HIP_MEMORY_SCOPE_AGENT);
        __hip_atomic_store(hxs + 3072, tagw | __builtin_bit_cast(unsigned short, (__bf16)h3),
                           __ATOMIC_RELAXED, __HIP_MEMORY_SCOPE_AGENT);

        pr0[(int64_t)t * HID]               = h0;   // fp32 outputs (normal cached)
        pr0[(int64_t)t * HID + rstride]     = h1;
        pr0[(int64_t)t * HID + 2 * rstride] = h2;
        pr0[(int64_t)t * HID + 3 * rstride] = h3;

        __syncthreads();   // A_lds reuse guard (this step's reads vs next stage's writes)
    }
}

extern "C" void kernel_launch(void* const* d_in, const int* in_sizes, int n_in,
                              void* d_out, int out_size, void* d_ws, size_t ws_size,
                              hipStream_t stream)
{
    const float* x    = (const float*)d_in[0];   // [64,1024,1024]
    const float* W    = (const float*)d_in[1];   // [2048,1024]
    const float* bias = (const float*)d_in[2];   // [1024]
    float* out = (float*)d_out;                  // [64,1024,1024]

    unsigned int* hx = (unsigned int*)d_ws;      // 2 slots x 64x1024 u32 = 512 KB

    hipMemsetAsync(hx, 0, 524288, stream);       // zero tags (expected tags >= 1)
    xproj_gemm<<<dim3(4096), dim3(256), 0, stream>>>(x, W, bias, out);
    rnn_scan<<<dim3(32), dim3(512), 0, stream>>>(W, out, hx);
}